// Round 8
// baseline (1139.476 us; speedup 1.0000x reference)
//
#include <hip/hip_runtime.h>
#include <stdint.h>

// ---------------------------------------------------------------------------
// RNN: S=512, B=64, IN=512, HID=1024, OUT=512, keep=0.7
//   Xh   = x @ Wihx^T + b_i2h                       (gemm_bt + usetup merged)
//   h_t  = Xh_t + h_{t-1} @ Whh^T                   (radix-2 pass1 + HS scan)
//   oc   = x@U1^T + h_prev@U2^T + h_new@Wo2^T + b'  (gemm_fused, fp32, *mask)
//   d_out = log_softmax(oc)                         (softmax, in-place)
//
// Round-12: correction rides the scan. In Hillis-Steele, chunk c is FINAL
// after the round with d > c (in that round's input buffer). So correction
// blocks for pairs 0..15 ride scans 2..6 (64/64/128/256/512 blocks), soaking
// the scans' idle CUs (scans run at 1.25 blocks/CU, latency-exposed), and the
// standalone correct shrinks to pairs 16..31. Rides read S from the scan's
// INPUT buffer (final for those chunks), write Harr slots (dead to scans 2+).
// Ride body = verbatim r6-proven correct body (SH-based LDS); standalone
// correct keeps its measured body. Also: softmax -> wave-per-row (8 f32/lane
// via 2x float4, pure shfl reduce, no LDS/barriers, 8192 blocks).
// ---------------------------------------------------------------------------

typedef unsigned short ushort_t;
typedef __attribute__((ext_vector_type(8))) __bf16 bf16x8;
typedef __attribute__((ext_vector_type(4))) float f32x4;

__device__ __forceinline__ ushort_t f2bf(float f) {
  union { float f; uint32_t u; } v; v.f = f;
  uint32_t r = v.u + 0x7fffu + ((v.u >> 16) & 1u);   // RNE
  return (ushort_t)(r >> 16);
}
__device__ __forceinline__ float bf2f(ushort_t b) {
  union { uint32_t u; float f; } v; v.u = ((uint32_t)b) << 16;
  return v.f;
}
__device__ __forceinline__ void gload16(const ushort_t* g, ushort_t* l) {
  __builtin_amdgcn_global_load_lds(
      (const __attribute__((address_space(1))) uint32_t*)g,
      (__attribute__((address_space(3))) uint32_t*)l, 16, 0, 0);
}

// ---------------------------------------------------------------- pack -----
// Ranges: [0,c0) xB | .. weights .. | [c6,c6+32K) bias' (wave/output) |
// [cB,cB+16M) mask bitpack | [cI,cI+32K) Harr slot0 zero (init fold).
__global__ __launch_bounds__(256) void pack_kernel(
    const float* __restrict__ x, const float* __restrict__ mask,
    const float* __restrict__ W_i2h,
    const float* __restrict__ W_i2o, const float* __restrict__ W_o2o,
    const float* __restrict__ b_i2o, const float* __restrict__ b_o2o,
    ushort_t* xB, ushort_t* Wihx, ushort_t* Whh, ushort_t* Wiox,
    ushort_t* Wioh, ushort_t* Wo1, ushort_t* Wo2, float* biasP,
    uint64_t* maskb, uint32_t* harr0) {
  int64_t i = (int64_t)blockIdx.x * blockDim.x + threadIdx.x;
  const int64_t c0 = 16777216, c1 = 17301504, c2 = 18350080, c3 = 18612224,
                c4 = 19136512, c5 = 19398656, c6 = 19922944,
                cB = 19955712,            // c6 + 32768 (64-aligned)
                cM = 36732928,            // cB + 16777216
                cI = 36765696;            // cM + 32768
  if (i < c0) { xB[i] = f2bf(x[i]); return; }
  if (i < c1) { int64_t j = i - c0; int r = j >> 9,  c = j & 511;  Wihx[j] = f2bf(W_i2h[(int64_t)r * 1536 + c]); return; }
  if (i < c2) { int64_t j = i - c1; int r = j >> 10, c = j & 1023; Whh[j]  = f2bf(W_i2h[(int64_t)r * 1536 + 512 + c]); return; }
  if (i < c3) { int64_t j = i - c2; int r = j >> 9,  c = j & 511;  Wiox[j] = f2bf(W_i2o[(int64_t)r * 1536 + c]); return; }
  if (i < c4) { int64_t j = i - c3; int r = j >> 10, c = j & 1023; Wioh[j] = f2bf(W_i2o[(int64_t)r * 1536 + 512 + c]); return; }
  if (i < c5) { int64_t j = i - c4; int r = j >> 9,  c = j & 511;  Wo1[j]  = f2bf(W_o2o[(int64_t)r * 1536 + c]); return; }
  if (i < c6) { int64_t j = i - c5; int r = j >> 10, c = j & 1023; Wo2[j]  = f2bf(W_o2o[(int64_t)r * 1536 + 512 + c]); return; }
  if (i < cB) {                       // bias' = Wo1·b_i2o + b_o2o, wave/output
    int64_t q = i - c6;               // c6 is 64-aligned -> wave == one n
    const int n = (int)(q >> 6), lane = (int)(q & 63);
    const float* wr = W_o2o + (int64_t)n * 1536;
    float s = 0.f;
#pragma unroll
    for (int k = 0; k < 8; ++k) {     // m = lane + 64k : coalesced in-wave
      const int m = lane + 64 * k;
      s += wr[m] * b_i2o[m];
    }
#pragma unroll
    for (int off = 32; off; off >>= 1) s += __shfl_xor(s, off, 64);
    if (lane == 0) biasP[n] = s + b_o2o[n];
    return;
  }
  if (i < cM) {                       // mask bit-pack (wave-aligned range)
    int64_t j = i - cB;
    float v = mask[j];
    uint64_t bits = __ballot(v != 0.0f);
    if ((j & 63) == 0) maskb[j >> 6] = bits;
    return;
  }
  if (i < cI) {                       // Harr global slot 0 = h_0 = 0
    harr0[i - cM] = 0;
  }
}

// -------------------------------------------------------------- usetup -----
// U1 = Wo1·Wiox [512,512], U2 = Wo1·Wioh [512,1024]. 48 ride blocks.
// Uses caller's LDS: AsF = SH, BsF = SH+4096.
__device__ void usetup_tile(ushort_t* SH,
    const ushort_t* __restrict__ Wo1, const ushort_t* __restrict__ Wiox,
    const ushort_t* __restrict__ Wioh, ushort_t* __restrict__ U1,
    ushort_t* __restrict__ U2, int job) {
  ushort_t* AsF = SH;
  ushort_t* BsF = SH + 4096;
  const ushort_t* Bm; ushort_t* Om; int mt, nt, ldb;
  if (job < 16) { mt = job >> 2; nt = job & 3; Bm = Wiox; Om = U1; ldb = 512; }
  else { job -= 16; mt = job >> 3; nt = job & 7; Bm = Wioh; Om = U2; ldb = 1024; }
  const int m0 = mt * 128, n0 = nt * 128;
  const int tid = threadIdx.x;
  const int w = tid >> 6, l = tid & 63;
  const int quad = l >> 4, l15 = l & 15;
  const int wm = (w & 1) * 64, wn = (w >> 1) * 64;
  const int r0 = tid >> 2, chunk = tid & 3;
  f32x4 acc[4][4] = {};
  for (int k0 = 0; k0 < 512; k0 += 32) {
    __syncthreads();
    gload16(Wo1 + (size_t)(m0 + r0) * 512 + k0 + chunk * 8,      &AsF[tid * 8]);
    gload16(Wo1 + (size_t)(m0 + r0 + 64) * 512 + k0 + chunk * 8, &AsF[2048 + tid * 8]);
#pragma unroll
    for (int rep = 0; rep < 2; ++rep) {
      const int idx = tid + 256 * rep;
      const int kk = idx & 31, n8 = idx >> 5;
      union { uint4 v; ushort_t s[8]; } u;
      u.v = *(const uint4*)(Bm + (size_t)(k0 + kk) * ldb + n0 + n8 * 8);
#pragma unroll
      for (int i = 0; i < 8; ++i) BsF[(n8 * 8 + i) * 32 + kk] = u.s[i];
    }
    __syncthreads();
    bf16x8 af[4], bfr[4];
#pragma unroll
    for (int i = 0; i < 4; ++i) af[i]  = *(const bf16x8*)&AsF[(wm + 16 * i + l15) * 32 + 8 * quad];
#pragma unroll
    for (int j = 0; j < 4; ++j) bfr[j] = *(const bf16x8*)&BsF[(wn + 16 * j + l15) * 32 + 8 * quad];
#pragma unroll
    for (int i = 0; i < 4; ++i)
#pragma unroll
      for (int j = 0; j < 4; ++j)
        acc[i][j] = __builtin_amdgcn_mfma_f32_16x16x32_bf16(af[i], bfr[j], acc[i][j], 0, 0, 0);
  }
#pragma unroll
  for (int i = 0; i < 4; ++i) {
    const int row = m0 + wm + 16 * i + 4 * quad;
#pragma unroll
    for (int j = 0; j < 4; ++j) {
      const int col = n0 + wn + 16 * j + l15;
#pragma unroll
      for (int r = 0; r < 4; ++r)
        Om[(size_t)(row + r) * ldb + col] = f2bf(acc[i][j][r]);
    }
  }
}

// ---------------------------------------------------------------- GEMM -----
// Xh: C[32768,1024] = A1@B1^T + bias (bf16 out). Prefetch double-buffered.
// Blocks >= 2048 do the usetup ride (U1/U2), sharing the same LDS block.
// LDS map: A bufs at 0 / 4096, B bufs at 8192 / 12288 (ushort offsets).
__global__ __launch_bounds__(256) void gemm_bt(
    const ushort_t* __restrict__ A1, int lda1, const ushort_t* __restrict__ B1, int K1,
    const float* __restrict__ bias, ushort_t* Cb, int Ntiles,
    const ushort_t* __restrict__ Wo1, const ushort_t* __restrict__ Wiox,
    const ushort_t* __restrict__ Wioh, ushort_t* __restrict__ U1,
    ushort_t* __restrict__ U2) {
  __shared__ __align__(16) ushort_t SH[16384];       // 32 KB
  if (blockIdx.x >= 2048) {
    usetup_tile(SH, Wo1, Wiox, Wioh, U1, U2, blockIdx.x - 2048);
    return;
  }
  const int mt = blockIdx.x & 255, nt = blockIdx.x >> 8;
  const int m0 = mt * 128, n0 = nt * 128;
  const int tid = threadIdx.x;
  const int w = tid >> 6, l = tid & 63;
  const int quad = l >> 4, l15 = l & 15;
  const int wm = (w & 1) * 64, wn = (w >> 1) * 64;
  const int r0 = tid >> 2, chunk = tid & 3;
  f32x4 acc[4][4] = {};
  gload16(A1 + (size_t)(m0 + r0) * lda1 + chunk * 8,      &SH[tid * 8]);
  gload16(A1 + (size_t)(m0 + r0 + 64) * lda1 + chunk * 8, &SH[2048 + tid * 8]);
  gload16(B1 + (size_t)(n0 + r0) * K1 + chunk * 8,        &SH[8192 + tid * 8]);
  gload16(B1 + (size_t)(n0 + r0 + 64) * K1 + chunk * 8,   &SH[8192 + 2048 + tid * 8]);
  const int NIT = K1 >> 5;
  for (int it = 0; it < NIT; ++it) {
    const int p = it & 1;
    const int ao = p * 4096, bo = 8192 + p * 4096;
    __syncthreads();
    if (it + 1 < NIT) {
      const int kn = (it + 1) * 32;
      const int an = (p ^ 1) * 4096, bn = 8192 + (p ^ 1) * 4096;
      gload16(A1 + (size_t)(m0 + r0) * lda1 + kn + chunk * 8,      &SH[an + tid * 8]);
      gload16(A1 + (size_t)(m0 + r0 + 64) * lda1 + kn + chunk * 8, &SH[an + 2048 + tid * 8]);
      gload16(B1 + (size_t)(n0 + r0) * K1 + kn + chunk * 8,        &SH[bn + tid * 8]);
      gload16(B1 + (size_t)(n0 + r0 + 64) * K1 + kn + chunk * 8,   &SH[bn + 2048 + tid * 8]);
    }
    bf16x8 af[4], bfr[4];
#pragma unroll
    for (int i = 0; i < 4; ++i) af[i]  = *(const bf16x8*)&SH[ao + (wm + 16 * i + l15) * 32 + 8 * quad];
#pragma unroll
    for (int j = 0; j < 4; ++j) bfr[j] = *(const bf16x8*)&SH[bo + (wn + 16 * j + l15) * 32 + 8 * quad];
#pragma unroll
    for (int i = 0; i < 4; ++i)
#pragma unroll
      for (int j = 0; j < 4; ++j)
        acc[i][j] = __builtin_amdgcn_mfma_f32_16x16x32_bf16(af[i], bfr[j], acc[i][j], 0, 0, 0);
  }
  const int N = Ntiles * 128;
#pragma unroll
  for (int i = 0; i < 4; ++i) {
    const int row = m0 + wm + 16 * i + 4 * quad;
#pragma unroll
    for (int j = 0; j < 4; ++j) {
      const int col = n0 + wn + 16 * j + l15;
      const float bv = bias[col];
#pragma unroll
      for (int r = 0; r < 4; ++r)
        Cb[(size_t)(row + r) * N + col] = f2bf(acc[i][j][r] + bv);
    }
  }
}

// ----------------------------------------------------- paired step tile ----
// 128 rows (two 64-row chunks) x 128 cols, NTERMS accumulated products
// (compile-time), K=1024 each, double-buffered (one barrier per iter).
// Loop-carried pointer increments (+32 elems/iter); for NTERMS=1 the term-
// switch folds away and A1r0/A1r1/B1 are dead (no register cost).
// Per-wave half h=(w&1) owns chunk h; caller passes Xh/Oh for that half.
// O_h = (gate? acc : 0) + X_h.  B row-major [N,1024], rows n0..n0+127.
// LDS map (ushort offsets): A bufs 0/4096 (128x32 each), B bufs 8192/12288.
template<int NTERMS>
__device__ void pair_tile128T(ushort_t* SH,
    const ushort_t* __restrict__ A0r0, const ushort_t* __restrict__ A0r1,
    const ushort_t* __restrict__ B0,
    const ushort_t* __restrict__ A1r0, const ushort_t* __restrict__ A1r1,
    const ushort_t* __restrict__ B1,
    int n0, const ushort_t* __restrict__ Xh, ushort_t* __restrict__ Oh,
    int gate) {
  const int tid = threadIdx.x;
  const int w = tid >> 6, l = tid & 63;
  const int quad = l >> 4, l15 = l & 15;
  const int wm = (w & 1) * 64, wn = (w >> 1) * 64;
  const int r0 = tid >> 2, chunk = tid & 3;
  const int thrA  = r0 * 1024 + chunk * 8;
  const int thrB0 = (n0 + r0) * 1024 + chunk * 8;
  const int thrB1 = (n0 + r0 + 64) * 1024 + chunk * 8;
  const ushort_t* ga0 = A0r0 + thrA;
  const ushort_t* ga1 = A0r1 + thrA;
  const ushort_t* gb0 = B0 + thrB0;
  const ushort_t* gb1 = B0 + thrB1;
  f32x4 acc[4][4] = {};
  gload16(ga0, &SH[tid * 8]);
  gload16(ga1, &SH[2048 + tid * 8]);
  gload16(gb0, &SH[8192 + tid * 8]);
  gload16(gb1, &SH[8192 + 2048 + tid * 8]);
  const int NIT = NTERMS * 32;
  for (int it = 0; it < NIT; ++it) {
    const int p = it & 1;
    const int ap = p * 4096, bp = 8192 + p * 4096;
    __syncthreads();              // drains buf[p] loads; protects buf[p^1] reuse
    if (it + 1 < NIT) {
      if (NTERMS == 2 && it == 31) {       // term boundary (compile-time dead
        ga0 = A1r0 + thrA; ga1 = A1r1 + thrA;   //  for NTERMS==1)
        gb0 = B1 + thrB0;  gb1 = B1 + thrB1;
      } else {
        ga0 += 32; ga1 += 32; gb0 += 32; gb1 += 32;
      }
      const int an = (p ^ 1) * 4096, bn = 8192 + (p ^ 1) * 4096;
      gload16(ga0, &SH[an + tid * 8]);
      gload16(ga1, &SH[an + 2048 + tid * 8]);
      gload16(gb0, &SH[bn + tid * 8]);
      gload16(gb1, &SH[bn + 2048 + tid * 8]);
    }
    bf16x8 af[4], bfr[4];
#pragma unroll
    for (int i = 0; i < 4; ++i) af[i]  = *(const bf16x8*)&SH[ap + (wm + 16 * i + l15) * 32 + 8 * quad];
#pragma unroll
    for (int j = 0; j < 4; ++j) bfr[j] = *(const bf16x8*)&SH[bp + (wn + 16 * j + l15) * 32 + 8 * quad];
#pragma unroll
    for (int i = 0; i < 4; ++i)
#pragma unroll
      for (int j = 0; j < 4; ++j)
        acc[i][j] = __builtin_amdgcn_mfma_f32_16x16x32_bf16(af[i], bfr[j], acc[i][j], 0, 0, 0);
  }
  // epilogue: this wave's rows live in chunk (w&1); local row = 16i+4quad+r
#pragma unroll
  for (int i = 0; i < 4; ++i) {
#pragma unroll
    for (int j = 0; j < 4; ++j) {
      const int col = n0 + wn + 16 * j + l15;
#pragma unroll
      for (int r = 0; r < 4; ++r) {
        const int lrow = 16 * i + 4 * quad + r;
        const size_t idx = (size_t)lrow * 1024 + col;
        float v = gate ? acc[i][j][r] : 0.0f;
        Oh[idx] = f2bf(v + bf2f(Xh[idx]));
      }
    }
  }
}

// Fast path for gated-off scan blocks: O = X (64x128 tile copy, 16 KB).
__device__ void copy_tile(const ushort_t* X, ushort_t* O, int n0) {
  const int t = threadIdx.x, r = t >> 2, q = t & 3;
  const uint4* src = (const uint4*)(X + (size_t)r * 1024 + n0 + q * 32);
  uint4* dst = (uint4*)(O + (size_t)r * 1024 + n0 + q * 32);
  dst[0] = src[0]; dst[1] = src[1]; dst[2] = src[2]; dst[3] = src[3];
}

// --------------------------------------------------------- power tile ------
// 128x128 tile of Om = Am @ Bm (plain [1024,1024] product, B^T into LDS).
// XCD-friendly decode: mt = t&7 so same-Am-rows blocks share an XCD L2.
// Uses caller LDS: AsF = SH, BsF = SH+4096.
__device__ void power_tile(ushort_t* SH,
                           const ushort_t* __restrict__ Am,
                           const ushort_t* __restrict__ Bm,
                           ushort_t* __restrict__ Om, int t) {
  ushort_t* AsF = SH;
  ushort_t* BsF = SH + 4096;
  const int mt = t & 7, nt = (t >> 3) & 7;
  const int m0 = mt * 128, n0 = nt * 128;
  const int tid = threadIdx.x;
  const int w = tid >> 6, l = tid & 63;
  const int quad = l >> 4, l15 = l & 15;
  const int wm = (w & 1) * 64, wn = (w >> 1) * 64;
  const int r0 = tid >> 2, chunk = tid & 3;
  f32x4 acc[4][4] = {};
  for (int k0 = 0; k0 < 1024; k0 += 32) {
    __syncthreads();
    gload16(Am + (size_t)(m0 + r0) * 1024 + k0 + chunk * 8,      &AsF[tid * 8]);
    gload16(Am + (size_t)(m0 + r0 + 64) * 1024 + k0 + chunk * 8, &AsF[2048 + tid * 8]);
#pragma unroll
    for (int rep = 0; rep < 2; ++rep) {
      const int idx = tid + 256 * rep;
      const int kk = idx & 31, n8 = idx >> 5;
      union { uint4 v; ushort_t s[8]; } u;
      u.v = *(const uint4*)(Bm + (size_t)(k0 + kk) * 1024 + n0 + n8 * 8);
#pragma unroll
      for (int i = 0; i < 8; ++i) BsF[(n8 * 8 + i) * 32 + kk] = u.s[i];
    }
    __syncthreads();
    bf16x8 af[4], bfr[4];
#pragma unroll
    for (int i = 0; i < 4; ++i) af[i]  = *(const bf16x8*)&AsF[(wm + 16 * i + l15) * 32 + 8 * quad];
#pragma unroll
    for (int j = 0; j < 4; ++j) bfr[j] = *(const bf16x8*)&BsF[(wn + 16 * j + l15) * 32 + 8 * quad];
#pragma unroll
    for (int i = 0; i < 4; ++i)
#pragma unroll
      for (int j = 0; j < 4; ++j)
        acc[i][j] = __builtin_amdgcn_mfma_f32_16x16x32_bf16(af[i], bfr[j], acc[i][j], 0, 0, 0);
  }
#pragma unroll
  for (int i = 0; i < 4; ++i) {
    const int row = m0 + wm + 16 * i + 4 * quad;
#pragma unroll
    for (int j = 0; j < 4; ++j) {
      const int col = n0 + wn + 16 * j + l15;
#pragma unroll
      for (int r = 0; r < 4; ++r)
        Om[(size_t)(row + r) * 1024 + col] = f2bf(acc[i][j][r]);
    }
  }
}

#define PWp(idx) (Pw + (size_t)(idx) * 1048576)
// Pw slots: 0:W2 1:W3 2:W4 3:W5 4:W6 5:W7 6:W8 7:W16 8:W32 9:W64 10:W128 11:W256

// -------------------------------------------------- correction ride body ---
// Verbatim r6-proven correct body, LDS via caller's SH (A bufs 0/4096,
// B bufs 8192/12288). Harr[slot j][pair chunks] = X_j + S@(W^j)^T.
__device__ void correct_ride(ushort_t* SH,
    const ushort_t* __restrict__ S, const ushort_t* __restrict__ XhB,
    ushort_t* __restrict__ Harr, const ushort_t* __restrict__ Whh,
    const ushort_t* __restrict__ Pw, int p_, int n0, int j) {
  const ushort_t* Wj = (j == 1) ? Whh : (Pw + (size_t)(j - 2) * 1048576);
  const ushort_t* Xs = (j == 1) ? XhB : (Harr + (size_t)j * 65536);
  ushort_t* XO = Harr + (size_t)j * 65536;
  const int tid = threadIdx.x;
  const int w = tid >> 6, l = tid & 63;
  const int quad = l >> 4, l15 = l & 15;
  const int wm = (w & 1) * 64, wn = (w >> 1) * 64;
  const int r0 = tid >> 2, chunk = tid & 3;
  f32x4 acc[4][4] = {};
  const ushort_t* a0 = S + (size_t)(2 * p_) * 524288 + (size_t)r0 * 1024;
  const ushort_t* a1 = S + (size_t)(2 * p_ + 1) * 524288 + (size_t)r0 * 1024;
  gload16(a0 + chunk * 8, &SH[tid * 8]);
  gload16(a1 + chunk * 8, &SH[2048 + tid * 8]);
  gload16(Wj + (size_t)(n0 + r0) * 1024 + chunk * 8,      &SH[8192 + tid * 8]);
  gload16(Wj + (size_t)(n0 + r0 + 64) * 1024 + chunk * 8, &SH[8192 + 2048 + tid * 8]);
  for (int it = 0; it < 32; ++it) {
    const int p = it & 1;
    const int ap = p * 4096, bp = 8192 + p * 4096;
    __syncthreads();
    if (it < 31) {
      const int kn = (it + 1) * 32;
      const int an = (p ^ 1) * 4096, bn = 8192 + (p ^ 1) * 4096;
      gload16(a0 + kn + chunk * 8, &SH[an + tid * 8]);
      gload16(a1 + kn + chunk * 8, &SH[an + 2048 + tid * 8]);
      gload16(Wj + (size_t)(n0 + r0) * 1024 + kn + chunk * 8,      &SH[bn + tid * 8]);
      gload16(Wj + (size_t)(n0 + r0 + 64) * 1024 + kn + chunk * 8, &SH[bn + 2048 + tid * 8]);
    }
    bf16x8 af[4], bfr[4];
#pragma unroll
    for (int i = 0; i < 4; ++i) af[i]  = *(const bf16x8*)&SH[ap + (wm + 16 * i + l15) * 32 + 8 * quad];
#pragma unroll
    for (int jj = 0; jj < 4; ++jj) bfr[jj] = *(const bf16x8*)&SH[bp + (wn + 16 * jj + l15) * 32 + 8 * quad];
#pragma unroll
    for (int i = 0; i < 4; ++i)
#pragma unroll
      for (int jj = 0; jj < 4; ++jj)
        acc[i][jj] = __builtin_amdgcn_mfma_f32_16x16x32_bf16(af[i], bfr[jj], acc[i][jj], 0, 0, 0);
  }
#pragma unroll
  for (int i = 0; i < 4; ++i) {
#pragma unroll
    for (int jj = 0; jj < 4; ++jj) {
      const int col = n0 + wn + 16 * jj + l15;
#pragma unroll
      for (int r = 0; r < 4; ++r) {
        const int gr = wm + 16 * i + 4 * quad + r;
        const int c = 2 * p_ + (gr >> 6);
        const size_t idx = (size_t)c * 524288 + (size_t)(gr & 63) * 1024 + col;
        XO[idx] = f2bf(acc[i][jj][r] + bf2f(Xs[idx]));
      }
    }
  }
}

// ------------------------------------------------------------ pass1 --------
// Radix-2 pass1, 3 launches (mode 1..3), 128-row paired blocks (32 pairs x
// 8 n0-tiles = 256 blocks/unit). Power ride-alongs occupy the LOW bids
// (NPOW = 64/128/256 for mode 1/2/3). Raw Xh in XhB slots 0..7 (x_1..x_8);
// prefixes X~_j in Harr slot j; P_6 scratch in Harr slot 1. Stride 524288.
//   L1: X~2=x2+x1·M ->H2 | P4=x4+x3·M ->H4 | P6=x6+x5·M ->H1 | P8=x8+x7·M ->H8
//       + ride W2
//   L2: X~3=x3+X~2·M ->H3 | X~4=P4+X~2·M^2 ->H4 | Q8=P8+P6·M^2 ->H8
//       + rides W3,W4
//   L3: X~5=x5+X~4·M ->H5 | X~6=P6+X~4·M^2 ->H6 | X~7=x7+P6·M+X~4·M^3 ->H7
//       (2-term) | X~8=Q8+X~4·M^4 ->H8   + rides W5,W6,W7,W8
// XCD-aware decode: inner%8 = pair_low (= bid%8 since NPOW%8==0).
__global__ __launch_bounds__(256) void pass_kernel(
    const ushort_t* __restrict__ XhB, ushort_t* __restrict__ Harr,
    const ushort_t* __restrict__ Whh, ushort_t* __restrict__ Pw, int mode) {
  __shared__ __align__(16) ushort_t SH[16384];       // 32 KB
  const int bid = blockIdx.x;
  const int npow = (mode == 1) ? 64 : ((mode == 2) ? 128 : 256);
  if (bid < npow) {                                  // power ride-alongs first
    const int pj = bid >> 6, t = bid & 63;
    const ushort_t *Am, *Bm; ushort_t* Om;
    if (mode == 1)      { Am = Whh;    Bm = Whh;    Om = PWp(0); }
    else if (mode == 2) {
      if (pj == 0) { Am = Whh;    Bm = PWp(0); Om = PWp(1); }       // W3
      else         { Am = PWp(0); Bm = PWp(0); Om = PWp(2); }       // W4
    } else {
      switch (pj) {
        case 0:  Am = Whh;    Bm = PWp(2); Om = PWp(3); break;      // W5
        case 1:  Am = PWp(0); Bm = PWp(2); Om = PWp(4); break;      // W6
        case 2:  Am = PWp(1); Bm = PWp(2); Om = PWp(5); break;      // W7
        default: Am = PWp(2); Bm = PWp(2); Om = PWp(6); break;      // W8
      }
    }
    power_tile(SH, Am, Bm, Om, t);
    return;
  }
  const int inner0 = bid - npow;
  const int u = inner0 >> 8, inner = inner0 & 255;
  // pair p_ = low3 | hi2<<3 (inner%8 = p_low -> XCD co-location), n0t = mid3
  const int p_ = (inner & 7) | (((inner >> 6) & 3) << 3);   // [0,32)
  const int n0 = ((inner >> 3) & 7) * 128;
#define HS_(s) (Harr + (size_t)(s) * 65536)
#define XS_(s) (XhB + (size_t)(s) * 65536)
  const ushort_t *A0, *B0, *A1 = nullptr, *B1 = nullptr, *X; ushort_t* O;
  int terms = 1;
  if (mode == 1) {
    const int as[4] = {0, 2, 4, 6}, xs[4] = {1, 3, 5, 7}, os[4] = {2, 4, 1, 8};
    A0 = XS_(as[u]); B0 = Whh; X = XS_(xs[u]); O = HS_(os[u]);
  } else if (mode == 2) {
    if (u == 0)      { A0 = HS_(2); B0 = Whh;    X = XS_(2); O = HS_(3); }
    else if (u == 1) { A0 = HS_(2); B0 = PWp(0); X = HS_(4); O = HS_(4); }
    else             { A0 = HS_(1); B0 = PWp(0); X = HS_(8); O = HS_(8); }
  } else {
    if (u == 0)      { A0 = HS_(4); B0 = Whh;    X = XS_(4); O = HS_(5); }
    else if (u == 1) { A0 = HS_(4); B0 = PWp(0); X = HS_(1); O = HS_(6); }
    else if (u == 2) { A0 = HS_(1); B0 = Whh; A1 = HS_(4); B1 = PWp(1);
                       terms = 2;               X = XS_(6); O = HS_(7); }
    else             { A0 = HS_(4); B0 = PWp(2); X = HS_(8); O = HS_(8); }
  }
  const size_t co0 = (size_t)(2 * p_) * 524288;
  const size_t co1 = co0 + 524288;
  const int half = (threadIdx.x >> 6) & 1;            // wave-uniform
  const size_t coh = half ? co1 : co0;
  if (terms == 2)
    pair_tile128T<2>(SH, A0 + co0, A0 + co1, B0, A1 + co0, A1 + co1, B1,
                     n0, X + coh, O + coh, 1);
  else
    pair_tile128T<1>(SH, A0 + co0, A0 + co1, B0, nullptr, nullptr, nullptr,
                     n0, X + coh, O + coh, 1);
}

// -------------------------------------------------------------- scan64 -----
// nw[c] = old[c] + (c>=d ? old[c-d]@Pv^T : 0). Chunk strides 524288.
// Block layout: [0,nride) power-squaring rides | [nride,nride+256) scan steps
// | [nride+256, +ncr*64) correction rides for pairs [crBase, crBase+ncr)
// (those chunks are FINAL in `old`, so correction can run here, soaking the
// scan's idle CUs). Pairs fully below d fast-copy; mixed pairs gate in-epi.
__global__ __launch_bounds__(256) void scan64(
    const ushort_t* __restrict__ old, ushort_t* __restrict__ nw,
    const ushort_t* __restrict__ Pv, int d,
    const ushort_t* __restrict__ Pra, ushort_t* __restrict__ Pwo, int nride,
    const ushort_t* __restrict__ XhB, ushort_t* __restrict__ Harr,
    const ushort_t* __restrict__ Whh, const ushort_t* __restrict__ Pw,
    int crBase, int ncr) {
  __shared__ __align__(16) ushort_t SH[16384];       // 32 KB
  if (blockIdx.x < nride) {
    power_tile(SH, Pra, Pra, Pwo, blockIdx.x);
    return;
  }
  if (blockIdx.x >= nride + 256) {                   // correction rides
    const int q = blockIdx.x - (nride + 256);
    const int pair = crBase + (q >> 6);
    const int r = q & 63;
    correct_ride(SH, old, XhB, Harr, Whh, Pw, pair, (r & 7) * 128,
                 (r >> 3) + 1);
    return;
  }
  const int bid = blockIdx.x - nride;                // nride%8==0 keeps bid%8
  const int p_ = (bid & 7) | (((bid >> 6) & 3) << 3);
  const int n0 = ((bid >> 3) & 7) * 128;
  const int c0 = 2 * p_, c1 = c0 + 1;
  if (c1 < d) {                                      // both halves dead: copy
    copy_tile(old + (size_t)c0 * 524288, nw + (size_t)c0 * 524288, n0);
    copy_tile(old + (size_t)c1 * 524288, nw + (size_t)c1 * 524288, n0);
    return;
  }
  const int ia0 = (c0 >= d) ? (c0 - d) : 0;          // clamped; gated in epi
  const int ia1 = c1 - d;                            // c1 >= d here
  const int half = (threadIdx.x >> 6) & 1;           // wave-uniform
  const int ch = half ? c1 : c0;
  const int gate = (ch >= d);
  pair_tile128T<1>(SH, old + (size_t)ia0 * 524288, old + (size_t)ia1 * 524288,
                   Pv, nullptr, nullptr, nullptr, n0,
                   old + (size_t)ch * 524288, nw + (size_t)ch * 524288, gate);
}

// ----------------------------------------------------------- correction ----
// Round-1-proven body, now covering only pairs 16..31 (pairs 0..15 were
// finished as scan rides). grid (128, 8): j = by+1:
//   Harr[slot j][c] = X_j[c] + S[c]@(W^j)^T, X_1 = XhB slot0, X_j = slot j.
__global__ __launch_bounds__(256) void correct_kernel(
    const ushort_t* __restrict__ S, const ushort_t* __restrict__ XhB,
    ushort_t* __restrict__ Harr, const ushort_t* __restrict__ Whh,
    const ushort_t* __restrict__ Pw) {
  __shared__ __align__(16) ushort_t AsF[2][4096];
  __shared__ __align__(16) ushort_t BsF[2][4096];
  const int p_ = 16 + (blockIdx.x >> 3);
  const int n0 = (blockIdx.x & 7) * 128;
  const int j = blockIdx.y + 1;
  const ushort_t* Wj = (j == 1) ? Whh : (Pw + (size_t)(j - 2) * 1048576);
  const ushort_t* Xs = (j == 1) ? XhB : (Harr + (size_t)j * 65536);
  ushort_t* XO = Harr + (size_t)j * 65536;
  const int tid = threadIdx.x;
  const int w = tid >> 6, l = tid & 63;
  const int quad = l >> 4, l15 = l & 15;
  const int wm = (w & 1) * 64, wn = (w >> 1) * 64;
  const int r0 = tid >> 2, chunk = tid & 3;
  f32x4 acc[4][4] = {};
  const ushort_t* a0 = S + (size_t)(2 * p_) * 524288 + (size_t)r0 * 1024;
  const ushort_t* a1 = S + (size_t)(2 * p_ + 1) * 524288 + (size_t)r0 * 1024;
  gload16(a0 + chunk * 8, &AsF[0][tid * 8]);
  gload16(a1 + chunk * 8, &AsF[0][2048 + tid * 8]);
  gload16(Wj + (size_t)(n0 + r0) * 1024 + chunk * 8,      &BsF[0][tid * 8]);
  gload16(Wj + (size_t)(n0 + r0 + 64) * 1024 + chunk * 8, &BsF[0][2048 + tid * 8]);
  for (int it = 0; it < 32; ++it) {
    const int p = it & 1;
    __syncthreads();
    if (it < 31) {
      const int kn = (it + 1) * 32;
      gload16(a0 + kn + chunk * 8, &AsF[p ^ 1][tid * 8]);
      gload16(a1 + kn + chunk * 8, &AsF[p ^ 1][2048 + tid * 8]);
      gload16(Wj + (size_t)(n0 + r0) * 1024 + kn + chunk * 8,      &BsF[p ^ 1][tid * 8]);
      gload16(Wj + (size_t)(n0 + r0 + 64) * 1024 + kn + chunk * 8, &BsF[p ^ 1][2048 + tid * 8]);
    }
    bf16x8 af[4], bfr[4];
#pragma unroll
    for (int i = 0; i < 4; ++i) af[i]  = *(const bf16x8*)&AsF[p][(wm + 16 * i + l15) * 32 + 8 * quad];
#pragma unroll
    for (int jj = 0; jj < 4; ++jj) bfr[jj] = *(const bf16x8*)&BsF[p][(wn + 16 * jj + l15) * 32 + 8 * quad];
#pragma unroll
    for (int i = 0; i < 4; ++i)
#pragma unroll
      for (int jj = 0; jj < 4; ++jj)
        acc[i][jj] = __builtin_amdgcn_mfma_f32_16x16x32_bf16(af[i], bfr[jj], acc[i][jj], 0, 0, 0);
  }
#pragma unroll
  for (int i = 0; i < 4; ++i) {
#pragma unroll
    for (int jj = 0; jj < 4; ++jj) {
      const int col = n0 + wn + 16 * jj + l15;
#pragma unroll
      for (int r = 0; r < 4; ++r) {
        const int gr = wm + 16 * i + 4 * quad + r;
        const int c = 2 * p_ + (gr >> 6);
        const size_t idx = (size_t)c * 524288 + (size_t)(gr & 63) * 1024 + col;
        XO[idx] = f2bf(acc[i][jj][r] + bf2f(Xs[idx]));
      }
    }
  }
}

// ---------------------------------------------------------- fused final ----
// oc = xB@U1^T + Hprev@U2^T + Hnew@Wo2^T + bias' ; out = oc * mask (bit mask)
__global__ __launch_bounds__(256) void gemm_fused(
    const ushort_t* __restrict__ xB, const ushort_t* __restrict__ U1,
    const ushort_t* __restrict__ Harr, const ushort_t* __restrict__ U2,
    const ushort_t* __restrict__ Wo2, const float* __restrict__ biasP,
    const uint64_t* __restrict__ maskb, float* __restrict__ out) {
  __shared__ __align__(16) ushort_t AsF[2][4096];
  __shared__ __align__(16) ushort_t BsF[2][4096];
  const int mt = blockIdx.x & 255, nt = blockIdx.x >> 8;
  const int m0 = mt * 128, n0 = nt * 128;
  const int tid = threadIdx.x;
  const int w = tid >> 6, l = tid & 63;
  const int quad = l >> 4, l15 = l & 15;
  const int wm = (w & 1) * 64, wn = (w >> 1) * 64;
  const int r0 = tid >> 2, chunk = tid & 3;
  f32x4 acc[4][4] = {};
  auto issue = [&](int it, int b) {
    const ushort_t *A, *B; int K, k0;
    if (it < 16)      { A = xB;           B = U1;  K = 512;  k0 = it << 5; }
    else if (it < 48) { A = Harr;         B = U2;  K = 1024; k0 = (it - 16) << 5; }
    else              { A = Harr + 65536; B = Wo2; K = 1024; k0 = (it - 48) << 5; }
    gload16(A + (size_t)(m0 + r0) * K + k0 + chunk * 8,      &AsF[b][tid * 8]);
    gload16(A + (size_t)(m0 + r0 + 64) * K + k0 + chunk * 8, &AsF[b][2048 + tid * 8]);
    gload16(B + (size_t)(n0 + r0) * K + k0 + chunk * 8,      &BsF[b][tid * 8]);
    gload16(B + (size_t)(n0 + r0 + 64) * K + k0 + chunk * 8, &BsF[b][2048 + tid * 8]);
  };
  issue(0, 0);
  for (int it = 0; it < 80; ++it) {
    const int p = it & 1;
    __syncthreads();
    if (it < 79) issue(it + 1, p ^ 1);
    bf16x8 af[4], bfr[4];
#pragma unroll
    for (int i = 0; i < 4; ++i) af[i]  = *(const bf16x8*)&AsF[p][(wm + 16 * i + l15) * 32 + 8 * quad];
#pragma unroll
    for (int j = 0; j < 4; ++j) bfr[j] = *(const bf16x8*)&BsF[p][(wn + 16 * j + l15) * 32 + 8 * quad];
#pragma unroll
    for (int i = 0; i < 4; ++i)
#pragma unroll
      for (int j = 0; j < 4; ++j)
        acc[i][j] = __builtin_amdgcn_mfma_f32_16x16x32_bf16(af[i], bfr[j], acc[i][j], 0, 0, 0);
  }
  const float INV_KEEP = 1.0f / 0.7f;     // exact: matches JAX f32 1.0/0.7
#pragma unroll
  for (int i = 0; i < 4; ++i) {
    const int row = m0 + wm + 16 * i + 4 * quad;
#pragma unroll
    for (int j = 0; j < 4; ++j) {
      const int col = n0 + wn + 16 * j + l15;
      const float bv = biasP[col];
#pragma unroll
      for (int r = 0; r < 4; ++r) {
        const size_t idx = (size_t)(row + r) * 512 + col;
        const uint64_t bits = maskb[idx >> 6];
        out[idx] = ((bits >> (idx & 63)) & 1) ? (acc[i][j][r] + bv) * INV_KEEP
                                              : 0.0f;
      }
    }
  }
}

// -------------------------------------------------------------- softmax ----
// Wave-per-row: 512 f32 = 8/lane (2x float4), pure shfl reduce, no LDS.
__global__ __launch_bounds__(256) void softmax_kernel(float* __restrict__ out) {
  const int row = blockIdx.x * 4 + (threadIdx.x >> 6);
  const int lane = threadIdx.x & 63;
  const size_t base = (size_t)row * 512 + (size_t)lane * 8;
  float4 v0 = *(const float4*)&out[base];
  float4 v1 = *(const float4*)&out[base + 4];
  float m = fmaxf(fmaxf(fmaxf(v0.x, v0.y), fmaxf(v0.z, v0.w)),
                  fmaxf(fmaxf(v1.x, v1.y), fmaxf(v1.z, v1.w)));
#pragma unroll
  for (int off = 32; off; off >>= 1) m = fmaxf(m, __shfl_xor(m, off, 64));
  float s = __expf(v0.x - m) + __expf(v0.y - m) + __expf(v0.z - m) +
            __expf(v0.w - m) + __expf(v1.x - m) + __expf(v1.y - m) +
            __expf(v1.z - m) + __expf(v1.w - m);
#pragma unroll
  for (int off = 32; off; off >>= 1) s += __shfl_xor(s, off, 64);
  const float sh = m + logf(s);
  v0.x -= sh; v0.y -= sh; v0.z -= sh; v0.w -= sh;
  v1.x -= sh; v1.y -= sh; v1.z -= sh; v1.w -= sh;
  *(float4*)&out[base] = v0;
  *(float4*)&out[base + 4] = v1;
}

// ---------------------------------------------------------------------------
extern "C" void kernel_launch(void* const* d_in, const int* in_sizes, int n_in,
                              void* d_out, int out_size, void* d_ws, size_t ws_size,
                              hipStream_t stream) {
  const float* x     = (const float*)d_in[0];
  const float* mask  = (const float*)d_in[1];
  const float* W_i2h = (const float*)d_in[2];
  const float* b_i2h = (const float*)d_in[3];
  const float* W_i2o = (const float*)d_in[4];
  const float* b_i2o = (const float*)d_in[5];
  const float* W_o2o = (const float*)d_in[6];
  const float* b_o2o = (const float*)d_in[7];
  float* out = (float*)d_out;

  char* ws = (char*)d_ws;
  const size_t NEED = 207749120;
  if (ws_size < NEED) return;
  ushort_t* xB   = (ushort_t*)(ws + 0);            // [32768,512] bf16
  ushort_t* XhB  = (ushort_t*)(ws + 33554432);     // [64 chunks][8 slots][64,1024]
  // SA/SB: strided overlays of XhB slots 1 / 3 (raw slots 1..7 dead after
  // pass1; slot 0 stays live for correction j=1). Chunk stride 524288.
  ushort_t* SA   = XhB + 65536;
  ushort_t* SB   = XhB + 3 * 65536;
  ushort_t* Harr = (ushort_t*)(ws + 100663296);    // [513][64,1024] bf16
  ushort_t* Pw   = (ushort_t*)(ws + 167903232);    // 12 x [1024,1024] powers
  ushort_t* U1   = (ushort_t*)(ws + 193069056);    // [512,512]
  ushort_t* U2   = (ushort_t*)(ws + 193593344);    // [512,1024]
  float* biasP   = (float*)(ws + 194641920);       // [512] fp32
  uint64_t* maskb = (uint64_t*)(ws + 195000320);   // [262144] u64 (2MB, in gap)
  ushort_t* Wihx = (ushort_t*)(ws + 201457664);
  ushort_t* Whh  = (ushort_t*)(ws + 202506240);
  ushort_t* Wiox = (ushort_t*)(ws + 204603392);
  ushort_t* Wioh = (ushort_t*)(ws + 205127680);
  ushort_t* Wo1  = (ushort_t*)(ws + 206176256);
  ushort_t* Wo2  = (ushort_t*)(ws + 206700544);

  // pack (+ bias' wave-reduce + mask bitpack + Harr slot0 init fold)
  hipLaunchKernelGGL(pack_kernel, dim3(143616), dim3(256), 0, stream,
                     x, mask, W_i2h, W_i2o, W_o2o, b_i2o, b_o2o,
                     xB, Wihx, Whh, Wiox, Wioh, Wo1, Wo2, biasP, maskb,
                     (uint32_t*)Harr);
  // Xh GEMM + usetup ride (48 extra blocks)
  hipLaunchKernelGGL(gemm_bt, dim3(2096), dim3(256), 0, stream,
                     xB, 512, Wihx, 512, b_i2h, XhB, 8,
                     Wo1, Wiox, Wioh, U1, U2);
  // radix-2 pass1: 3 launches, rides first (W2 / W3,W4 / W5..W8)
  hipLaunchKernelGGL(pass_kernel, dim3(1088), dim3(256), 0, stream,
                     XhB, Harr, Whh, Pw, 1);
  hipLaunchKernelGGL(pass_kernel, dim3(896), dim3(256), 0, stream,
                     XhB, Harr, Whh, Pw, 2);
  hipLaunchKernelGGL(pass_kernel, dim3(1280), dim3(256), 0, stream,
                     XhB, Harr, Whh, Pw, 3);
  // Hillis-Steele scan (final S in SA). Power squarings W16..W256 ride
  // scans 1..5; correction rides for finalized pairs join scans 2..6:
  //   scan2: pair 0 | scan3: pair 1 | scan4: pairs 2-3 | scan5: 4-7
  //   scan6: 8-15 | standalone correct: 16-31.
  hipLaunchKernelGGL(scan64, dim3(320), dim3(256), 0, stream, Harr, SB, PWp(6),  1, PWp(6),  PWp(7),  64,
                     XhB, Harr, Whh, Pw, 0, 0);
  hipLaunchKernelGGL(scan64, dim3(384), dim3(256), 0, stream, SB, SA, PWp(7),  2, PWp(7),  PWp(8),  64,
                     XhB, Harr, Whh, Pw, 0, 1);
  hipLaunchKernelGGL(scan64, dim3(384), dim3(256), 0, stream, SA, SB, PWp(8),  4, PWp(8),  PWp(9),  64,
                     XhB, Harr, Whh, Pw, 1, 1);
  hipLaunchKernelGGL(scan64, dim3(448), dim3(256), 0, stream, SB, SA, PWp(9),  8, PWp(9),  PWp(10), 64,
                     XhB, Harr, Whh, Pw, 2, 2);
  hipLaunchKernelGGL(scan64, dim3(576), dim3(256), 0, stream, SA, SB, PWp(10), 16, PWp(10), PWp(11), 64,
                     XhB, Harr, Whh, Pw, 4, 4);
  hipLaunchKernelGGL(scan64, dim3(768), dim3(256), 0, stream, SB, SA, PWp(11), 32,
                     (const ushort_t*)nullptr, (ushort_t*)nullptr, 0,
                     XhB, Harr, Whh, Pw, 8, 8);
  // correction tail: pairs 16..31 (chunks 32-63), j=1..8
  hipLaunchKernelGGL(correct_kernel, dim3(dim3(128, 8)), dim3(256), 0, stream,
                     SA, XhB, Harr, Whh, Pw);
  // oc = xB@U1^T + Hprev@U2^T + Hnew@Wo2^T + bias', *mask -> d_out
  hipLaunchKernelGGL(gemm_fused, dim3(1024), dim3(256), 0, stream,
                     xB, U1, Harr, U2, Wo2, biasP, maskb, out);
  hipLaunchKernelGGL(softmax_kernel, dim3(8192), dim3(256), 0, stream, out);
}

// Round 9
// 1074.664 us; speedup vs baseline: 1.0603x; 1.0603x over previous
//
#include <hip/hip_runtime.h>
#include <stdint.h>

// ---------------------------------------------------------------------------
// RNN: S=512, B=64, IN=512, HID=1024, OUT=512, keep=0.7
//   Xh   = x @ Wihx^T + b_i2h                       (gemm_bt + usetup merged)
//   h_t  = Xh_t + h_{t-1} @ Whh^T                   (radix-2 pass1 + HS scan)
//   oc   = x@U1^T + h_prev@U2^T + h_new@Wo2^T + b'  (gemm_fused BK=64, *mask)
//   d_out = log_softmax(oc)                         (softmax, wave-per-row)
//
// Round-13: (1) REVERT r12's correction-rides (net -26us: rides extended the
// serial scan chain more than they shrank correct — scans back to r7 shape,
// correct back to full 256x8). Keep r12's wave-per-row softmax (independent).
// (2) gemm_fused: fuse two K-steps per barrier (BK=64). Keeps the proven
// [128][32] LDS sub-tile layout (2 sub-tiles per buffer -> identical bank
// behavior + MFMA addressing), issues both sub-tiles' loads per iteration:
// 40 iters instead of 80, 32 MFMA/wave per barrier instead of 16. LDS 64KB
// -> 2 blocks/CU = measured residency anyway; barrier-drain cost halves.
// ---------------------------------------------------------------------------

typedef unsigned short ushort_t;
typedef __attribute__((ext_vector_type(8))) __bf16 bf16x8;
typedef __attribute__((ext_vector_type(4))) float f32x4;

__device__ __forceinline__ ushort_t f2bf(float f) {
  union { float f; uint32_t u; } v; v.f = f;
  uint32_t r = v.u + 0x7fffu + ((v.u >> 16) & 1u);   // RNE
  return (ushort_t)(r >> 16);
}
__device__ __forceinline__ float bf2f(ushort_t b) {
  union { uint32_t u; float f; } v; v.u = ((uint32_t)b) << 16;
  return v.f;
}
__device__ __forceinline__ void gload16(const ushort_t* g, ushort_t* l) {
  __builtin_amdgcn_global_load_lds(
      (const __attribute__((address_space(1))) uint32_t*)g,
      (__attribute__((address_space(3))) uint32_t*)l, 16, 0, 0);
}

// ---------------------------------------------------------------- pack -----
// Ranges: [0,c0) xB | .. weights .. | [c6,c6+32K) bias' (wave/output) |
// [cB,cB+16M) mask bitpack | [cI,cI+32K) Harr slot0 zero (init fold).
__global__ __launch_bounds__(256) void pack_kernel(
    const float* __restrict__ x, const float* __restrict__ mask,
    const float* __restrict__ W_i2h,
    const float* __restrict__ W_i2o, const float* __restrict__ W_o2o,
    const float* __restrict__ b_i2o, const float* __restrict__ b_o2o,
    ushort_t* xB, ushort_t* Wihx, ushort_t* Whh, ushort_t* Wiox,
    ushort_t* Wioh, ushort_t* Wo1, ushort_t* Wo2, float* biasP,
    uint64_t* maskb, uint32_t* harr0) {
  int64_t i = (int64_t)blockIdx.x * blockDim.x + threadIdx.x;
  const int64_t c0 = 16777216, c1 = 17301504, c2 = 18350080, c3 = 18612224,
                c4 = 19136512, c5 = 19398656, c6 = 19922944,
                cB = 19955712,            // c6 + 32768 (64-aligned)
                cM = 36732928,            // cB + 16777216
                cI = 36765696;            // cM + 32768
  if (i < c0) { xB[i] = f2bf(x[i]); return; }
  if (i < c1) { int64_t j = i - c0; int r = j >> 9,  c = j & 511;  Wihx[j] = f2bf(W_i2h[(int64_t)r * 1536 + c]); return; }
  if (i < c2) { int64_t j = i - c1; int r = j >> 10, c = j & 1023; Whh[j]  = f2bf(W_i2h[(int64_t)r * 1536 + 512 + c]); return; }
  if (i < c3) { int64_t j = i - c2; int r = j >> 9,  c = j & 511;  Wiox[j] = f2bf(W_i2o[(int64_t)r * 1536 + c]); return; }
  if (i < c4) { int64_t j = i - c3; int r = j >> 10, c = j & 1023; Wioh[j] = f2bf(W_i2o[(int64_t)r * 1536 + 512 + c]); return; }
  if (i < c5) { int64_t j = i - c4; int r = j >> 9,  c = j & 511;  Wo1[j]  = f2bf(W_o2o[(int64_t)r * 1536 + c]); return; }
  if (i < c6) { int64_t j = i - c5; int r = j >> 10, c = j & 1023; Wo2[j]  = f2bf(W_o2o[(int64_t)r * 1536 + 512 + c]); return; }
  if (i < cB) {                       // bias' = Wo1·b_i2o + b_o2o, wave/output
    int64_t q = i - c6;               // c6 is 64-aligned -> wave == one n
    const int n = (int)(q >> 6), lane = (int)(q & 63);
    const float* wr = W_o2o + (int64_t)n * 1536;
    float s = 0.f;
#pragma unroll
    for (int k = 0; k < 8; ++k) {     // m = lane + 64k : coalesced in-wave
      const int m = lane + 64 * k;
      s += wr[m] * b_i2o[m];
    }
#pragma unroll
    for (int off = 32; off; off >>= 1) s += __shfl_xor(s, off, 64);
    if (lane == 0) biasP[n] = s + b_o2o[n];
    return;
  }
  if (i < cM) {                       // mask bit-pack (wave-aligned range)
    int64_t j = i - cB;
    float v = mask[j];
    uint64_t bits = __ballot(v != 0.0f);
    if ((j & 63) == 0) maskb[j >> 6] = bits;
    return;
  }
  if (i < cI) {                       // Harr global slot 0 = h_0 = 0
    harr0[i - cM] = 0;
  }
}

// -------------------------------------------------------------- usetup -----
// U1 = Wo1·Wiox [512,512], U2 = Wo1·Wioh [512,1024]. 48 ride blocks.
// Uses caller's LDS: AsF = SH, BsF = SH+4096.
__device__ void usetup_tile(ushort_t* SH,
    const ushort_t* __restrict__ Wo1, const ushort_t* __restrict__ Wiox,
    const ushort_t* __restrict__ Wioh, ushort_t* __restrict__ U1,
    ushort_t* __restrict__ U2, int job) {
  ushort_t* AsF = SH;
  ushort_t* BsF = SH + 4096;
  const ushort_t* Bm; ushort_t* Om; int mt, nt, ldb;
  if (job < 16) { mt = job >> 2; nt = job & 3; Bm = Wiox; Om = U1; ldb = 512; }
  else { job -= 16; mt = job >> 3; nt = job & 7; Bm = Wioh; Om = U2; ldb = 1024; }
  const int m0 = mt * 128, n0 = nt * 128;
  const int tid = threadIdx.x;
  const int w = tid >> 6, l = tid & 63;
  const int quad = l >> 4, l15 = l & 15;
  const int wm = (w & 1) * 64, wn = (w >> 1) * 64;
  const int r0 = tid >> 2, chunk = tid & 3;
  f32x4 acc[4][4] = {};
  for (int k0 = 0; k0 < 512; k0 += 32) {
    __syncthreads();
    gload16(Wo1 + (size_t)(m0 + r0) * 512 + k0 + chunk * 8,      &AsF[tid * 8]);
    gload16(Wo1 + (size_t)(m0 + r0 + 64) * 512 + k0 + chunk * 8, &AsF[2048 + tid * 8]);
#pragma unroll
    for (int rep = 0; rep < 2; ++rep) {
      const int idx = tid + 256 * rep;
      const int kk = idx & 31, n8 = idx >> 5;
      union { uint4 v; ushort_t s[8]; } u;
      u.v = *(const uint4*)(Bm + (size_t)(k0 + kk) * ldb + n0 + n8 * 8);
#pragma unroll
      for (int i = 0; i < 8; ++i) BsF[(n8 * 8 + i) * 32 + kk] = u.s[i];
    }
    __syncthreads();
    bf16x8 af[4], bfr[4];
#pragma unroll
    for (int i = 0; i < 4; ++i) af[i]  = *(const bf16x8*)&AsF[(wm + 16 * i + l15) * 32 + 8 * quad];
#pragma unroll
    for (int j = 0; j < 4; ++j) bfr[j] = *(const bf16x8*)&BsF[(wn + 16 * j + l15) * 32 + 8 * quad];
#pragma unroll
    for (int i = 0; i < 4; ++i)
#pragma unroll
      for (int j = 0; j < 4; ++j)
        acc[i][j] = __builtin_amdgcn_mfma_f32_16x16x32_bf16(af[i], bfr[j], acc[i][j], 0, 0, 0);
  }
#pragma unroll
  for (int i = 0; i < 4; ++i) {
    const int row = m0 + wm + 16 * i + 4 * quad;
#pragma unroll
    for (int j = 0; j < 4; ++j) {
      const int col = n0 + wn + 16 * j + l15;
#pragma unroll
      for (int r = 0; r < 4; ++r)
        Om[(size_t)(row + r) * ldb + col] = f2bf(acc[i][j][r]);
    }
  }
}

// ---------------------------------------------------------------- GEMM -----
// Xh: C[32768,1024] = A1@B1^T + bias (bf16 out). Prefetch double-buffered.
// Blocks >= 2048 do the usetup ride (U1/U2), sharing the same LDS block.
// LDS map: A bufs at 0 / 4096, B bufs at 8192 / 12288 (ushort offsets).
__global__ __launch_bounds__(256) void gemm_bt(
    const ushort_t* __restrict__ A1, int lda1, const ushort_t* __restrict__ B1, int K1,
    const float* __restrict__ bias, ushort_t* Cb, int Ntiles,
    const ushort_t* __restrict__ Wo1, const ushort_t* __restrict__ Wiox,
    const ushort_t* __restrict__ Wioh, ushort_t* __restrict__ U1,
    ushort_t* __restrict__ U2) {
  __shared__ __align__(16) ushort_t SH[16384];       // 32 KB
  if (blockIdx.x >= 2048) {
    usetup_tile(SH, Wo1, Wiox, Wioh, U1, U2, blockIdx.x - 2048);
    return;
  }
  const int mt = blockIdx.x & 255, nt = blockIdx.x >> 8;
  const int m0 = mt * 128, n0 = nt * 128;
  const int tid = threadIdx.x;
  const int w = tid >> 6, l = tid & 63;
  const int quad = l >> 4, l15 = l & 15;
  const int wm = (w & 1) * 64, wn = (w >> 1) * 64;
  const int r0 = tid >> 2, chunk = tid & 3;
  f32x4 acc[4][4] = {};
  gload16(A1 + (size_t)(m0 + r0) * lda1 + chunk * 8,      &SH[tid * 8]);
  gload16(A1 + (size_t)(m0 + r0 + 64) * lda1 + chunk * 8, &SH[2048 + tid * 8]);
  gload16(B1 + (size_t)(n0 + r0) * K1 + chunk * 8,        &SH[8192 + tid * 8]);
  gload16(B1 + (size_t)(n0 + r0 + 64) * K1 + chunk * 8,   &SH[8192 + 2048 + tid * 8]);
  const int NIT = K1 >> 5;
  for (int it = 0; it < NIT; ++it) {
    const int p = it & 1;
    const int ao = p * 4096, bo = 8192 + p * 4096;
    __syncthreads();
    if (it + 1 < NIT) {
      const int kn = (it + 1) * 32;
      const int an = (p ^ 1) * 4096, bn = 8192 + (p ^ 1) * 4096;
      gload16(A1 + (size_t)(m0 + r0) * lda1 + kn + chunk * 8,      &SH[an + tid * 8]);
      gload16(A1 + (size_t)(m0 + r0 + 64) * lda1 + kn + chunk * 8, &SH[an + 2048 + tid * 8]);
      gload16(B1 + (size_t)(n0 + r0) * K1 + kn + chunk * 8,        &SH[bn + tid * 8]);
      gload16(B1 + (size_t)(n0 + r0 + 64) * K1 + kn + chunk * 8,   &SH[bn + 2048 + tid * 8]);
    }
    bf16x8 af[4], bfr[4];
#pragma unroll
    for (int i = 0; i < 4; ++i) af[i]  = *(const bf16x8*)&SH[ao + (wm + 16 * i + l15) * 32 + 8 * quad];
#pragma unroll
    for (int j = 0; j < 4; ++j) bfr[j] = *(const bf16x8*)&SH[bo + (wn + 16 * j + l15) * 32 + 8 * quad];
#pragma unroll
    for (int i = 0; i < 4; ++i)
#pragma unroll
      for (int j = 0; j < 4; ++j)
        acc[i][j] = __builtin_amdgcn_mfma_f32_16x16x32_bf16(af[i], bfr[j], acc[i][j], 0, 0, 0);
  }
  const int N = Ntiles * 128;
#pragma unroll
  for (int i = 0; i < 4; ++i) {
    const int row = m0 + wm + 16 * i + 4 * quad;
#pragma unroll
    for (int j = 0; j < 4; ++j) {
      const int col = n0 + wn + 16 * j + l15;
      const float bv = bias[col];
#pragma unroll
      for (int r = 0; r < 4; ++r)
        Cb[(size_t)(row + r) * N + col] = f2bf(acc[i][j][r] + bv);
    }
  }
}

// ----------------------------------------------------- paired step tile ----
// 128 rows (two 64-row chunks) x 128 cols, NTERMS accumulated products
// (compile-time), K=1024 each, double-buffered (one barrier per iter).
// Loop-carried pointer increments (+32 elems/iter); for NTERMS=1 the term-
// switch folds away and A1r0/A1r1/B1 are dead (no register cost).
// Per-wave half h=(w&1) owns chunk h; caller passes Xh/Oh for that half.
// O_h = (gate? acc : 0) + X_h.  B row-major [N,1024], rows n0..n0+127.
// LDS map (ushort offsets): A bufs 0/4096 (128x32 each), B bufs 8192/12288.
template<int NTERMS>
__device__ void pair_tile128T(ushort_t* SH,
    const ushort_t* __restrict__ A0r0, const ushort_t* __restrict__ A0r1,
    const ushort_t* __restrict__ B0,
    const ushort_t* __restrict__ A1r0, const ushort_t* __restrict__ A1r1,
    const ushort_t* __restrict__ B1,
    int n0, const ushort_t* __restrict__ Xh, ushort_t* __restrict__ Oh,
    int gate) {
  const int tid = threadIdx.x;
  const int w = tid >> 6, l = tid & 63;
  const int quad = l >> 4, l15 = l & 15;
  const int wm = (w & 1) * 64, wn = (w >> 1) * 64;
  const int r0 = tid >> 2, chunk = tid & 3;
  const int thrA  = r0 * 1024 + chunk * 8;
  const int thrB0 = (n0 + r0) * 1024 + chunk * 8;
  const int thrB1 = (n0 + r0 + 64) * 1024 + chunk * 8;
  const ushort_t* ga0 = A0r0 + thrA;
  const ushort_t* ga1 = A0r1 + thrA;
  const ushort_t* gb0 = B0 + thrB0;
  const ushort_t* gb1 = B0 + thrB1;
  f32x4 acc[4][4] = {};
  gload16(ga0, &SH[tid * 8]);
  gload16(ga1, &SH[2048 + tid * 8]);
  gload16(gb0, &SH[8192 + tid * 8]);
  gload16(gb1, &SH[8192 + 2048 + tid * 8]);
  const int NIT = NTERMS * 32;
  for (int it = 0; it < NIT; ++it) {
    const int p = it & 1;
    const int ap = p * 4096, bp = 8192 + p * 4096;
    __syncthreads();              // drains buf[p] loads; protects buf[p^1] reuse
    if (it + 1 < NIT) {
      if (NTERMS == 2 && it == 31) {       // term boundary (compile-time dead
        ga0 = A1r0 + thrA; ga1 = A1r1 + thrA;   //  for NTERMS==1)
        gb0 = B1 + thrB0;  gb1 = B1 + thrB1;
      } else {
        ga0 += 32; ga1 += 32; gb0 += 32; gb1 += 32;
      }
      const int an = (p ^ 1) * 4096, bn = 8192 + (p ^ 1) * 4096;
      gload16(ga0, &SH[an + tid * 8]);
      gload16(ga1, &SH[an + 2048 + tid * 8]);
      gload16(gb0, &SH[bn + tid * 8]);
      gload16(gb1, &SH[bn + 2048 + tid * 8]);
    }
    bf16x8 af[4], bfr[4];
#pragma unroll
    for (int i = 0; i < 4; ++i) af[i]  = *(const bf16x8*)&SH[ap + (wm + 16 * i + l15) * 32 + 8 * quad];
#pragma unroll
    for (int j = 0; j < 4; ++j) bfr[j] = *(const bf16x8*)&SH[bp + (wn + 16 * j + l15) * 32 + 8 * quad];
#pragma unroll
    for (int i = 0; i < 4; ++i)
#pragma unroll
      for (int j = 0; j < 4; ++j)
        acc[i][j] = __builtin_amdgcn_mfma_f32_16x16x32_bf16(af[i], bfr[j], acc[i][j], 0, 0, 0);
  }
  // epilogue: this wave's rows live in chunk (w&1); local row = 16i+4quad+r
#pragma unroll
  for (int i = 0; i < 4; ++i) {
#pragma unroll
    for (int j = 0; j < 4; ++j) {
      const int col = n0 + wn + 16 * j + l15;
#pragma unroll
      for (int r = 0; r < 4; ++r) {
        const int lrow = 16 * i + 4 * quad + r;
        const size_t idx = (size_t)lrow * 1024 + col;
        float v = gate ? acc[i][j][r] : 0.0f;
        Oh[idx] = f2bf(v + bf2f(Xh[idx]));
      }
    }
  }
}

// Fast path for gated-off scan blocks: O = X (64x128 tile copy, 16 KB).
__device__ void copy_tile(const ushort_t* X, ushort_t* O, int n0) {
  const int t = threadIdx.x, r = t >> 2, q = t & 3;
  const uint4* src = (const uint4*)(X + (size_t)r * 1024 + n0 + q * 32);
  uint4* dst = (uint4*)(O + (size_t)r * 1024 + n0 + q * 32);
  dst[0] = src[0]; dst[1] = src[1]; dst[2] = src[2]; dst[3] = src[3];
}

// --------------------------------------------------------- power tile ------
// 128x128 tile of Om = Am @ Bm (plain [1024,1024] product, B^T into LDS).
// XCD-friendly decode: mt = t&7 so same-Am-rows blocks share an XCD L2.
// Uses caller LDS: AsF = SH, BsF = SH+4096.
__device__ void power_tile(ushort_t* SH,
                           const ushort_t* __restrict__ Am,
                           const ushort_t* __restrict__ Bm,
                           ushort_t* __restrict__ Om, int t) {
  ushort_t* AsF = SH;
  ushort_t* BsF = SH + 4096;
  const int mt = t & 7, nt = (t >> 3) & 7;
  const int m0 = mt * 128, n0 = nt * 128;
  const int tid = threadIdx.x;
  const int w = tid >> 6, l = tid & 63;
  const int quad = l >> 4, l15 = l & 15;
  const int wm = (w & 1) * 64, wn = (w >> 1) * 64;
  const int r0 = tid >> 2, chunk = tid & 3;
  f32x4 acc[4][4] = {};
  for (int k0 = 0; k0 < 1024; k0 += 32) {
    __syncthreads();
    gload16(Am + (size_t)(m0 + r0) * 1024 + k0 + chunk * 8,      &AsF[tid * 8]);
    gload16(Am + (size_t)(m0 + r0 + 64) * 1024 + k0 + chunk * 8, &AsF[2048 + tid * 8]);
#pragma unroll
    for (int rep = 0; rep < 2; ++rep) {
      const int idx = tid + 256 * rep;
      const int kk = idx & 31, n8 = idx >> 5;
      union { uint4 v; ushort_t s[8]; } u;
      u.v = *(const uint4*)(Bm + (size_t)(k0 + kk) * 1024 + n0 + n8 * 8);
#pragma unroll
      for (int i = 0; i < 8; ++i) BsF[(n8 * 8 + i) * 32 + kk] = u.s[i];
    }
    __syncthreads();
    bf16x8 af[4], bfr[4];
#pragma unroll
    for (int i = 0; i < 4; ++i) af[i]  = *(const bf16x8*)&AsF[(wm + 16 * i + l15) * 32 + 8 * quad];
#pragma unroll
    for (int j = 0; j < 4; ++j) bfr[j] = *(const bf16x8*)&BsF[(wn + 16 * j + l15) * 32 + 8 * quad];
#pragma unroll
    for (int i = 0; i < 4; ++i)
#pragma unroll
      for (int j = 0; j < 4; ++j)
        acc[i][j] = __builtin_amdgcn_mfma_f32_16x16x32_bf16(af[i], bfr[j], acc[i][j], 0, 0, 0);
  }
#pragma unroll
  for (int i = 0; i < 4; ++i) {
    const int row = m0 + wm + 16 * i + 4 * quad;
#pragma unroll
    for (int j = 0; j < 4; ++j) {
      const int col = n0 + wn + 16 * j + l15;
#pragma unroll
      for (int r = 0; r < 4; ++r)
        Om[(size_t)(row + r) * 1024 + col] = f2bf(acc[i][j][r]);
    }
  }
}

#define PWp(idx) (Pw + (size_t)(idx) * 1048576)
// Pw slots: 0:W2 1:W3 2:W4 3:W5 4:W6 5:W7 6:W8 7:W16 8:W32 9:W64 10:W128 11:W256

// ------------------------------------------------------------ pass1 --------
// Radix-2 pass1, 3 launches (mode 1..3), 128-row paired blocks (32 pairs x
// 8 n0-tiles = 256 blocks/unit). Power ride-alongs occupy the LOW bids
// (NPOW = 64/128/256 for mode 1/2/3). Raw Xh in XhB slots 0..7 (x_1..x_8);
// prefixes X~_j in Harr slot j; P_6 scratch in Harr slot 1. Stride 524288.
//   L1: X~2=x2+x1·M ->H2 | P4=x4+x3·M ->H4 | P6=x6+x5·M ->H1 | P8=x8+x7·M ->H8
//       + ride W2
//   L2: X~3=x3+X~2·M ->H3 | X~4=P4+X~2·M^2 ->H4 | Q8=P8+P6·M^2 ->H8
//       + rides W3,W4
//   L3: X~5=x5+X~4·M ->H5 | X~6=P6+X~4·M^2 ->H6 | X~7=x7+P6·M+X~4·M^3 ->H7
//       (2-term) | X~8=Q8+X~4·M^4 ->H8   + rides W5,W6,W7,W8
// XCD-aware decode: inner%8 = pair_low (= bid%8 since NPOW%8==0).
__global__ __launch_bounds__(256) void pass_kernel(
    const ushort_t* __restrict__ XhB, ushort_t* __restrict__ Harr,
    const ushort_t* __restrict__ Whh, ushort_t* __restrict__ Pw, int mode) {
  __shared__ __align__(16) ushort_t SH[16384];       // 32 KB
  const int bid = blockIdx.x;
  const int npow = (mode == 1) ? 64 : ((mode == 2) ? 128 : 256);
  if (bid < npow) {                                  // power ride-alongs first
    const int pj = bid >> 6, t = bid & 63;
    const ushort_t *Am, *Bm; ushort_t* Om;
    if (mode == 1)      { Am = Whh;    Bm = Whh;    Om = PWp(0); }
    else if (mode == 2) {
      if (pj == 0) { Am = Whh;    Bm = PWp(0); Om = PWp(1); }       // W3
      else         { Am = PWp(0); Bm = PWp(0); Om = PWp(2); }       // W4
    } else {
      switch (pj) {
        case 0:  Am = Whh;    Bm = PWp(2); Om = PWp(3); break;      // W5
        case 1:  Am = PWp(0); Bm = PWp(2); Om = PWp(4); break;      // W6
        case 2:  Am = PWp(1); Bm = PWp(2); Om = PWp(5); break;      // W7
        default: Am = PWp(2); Bm = PWp(2); Om = PWp(6); break;      // W8
      }
    }
    power_tile(SH, Am, Bm, Om, t);
    return;
  }
  const int inner0 = bid - npow;
  const int u = inner0 >> 8, inner = inner0 & 255;
  // pair p_ = low3 | hi2<<3 (inner%8 = p_low -> XCD co-location), n0t = mid3
  const int p_ = (inner & 7) | (((inner >> 6) & 3) << 3);   // [0,32)
  const int n0 = ((inner >> 3) & 7) * 128;
#define HS_(s) (Harr + (size_t)(s) * 65536)
#define XS_(s) (XhB + (size_t)(s) * 65536)
  const ushort_t *A0, *B0, *A1 = nullptr, *B1 = nullptr, *X; ushort_t* O;
  int terms = 1;
  if (mode == 1) {
    const int as[4] = {0, 2, 4, 6}, xs[4] = {1, 3, 5, 7}, os[4] = {2, 4, 1, 8};
    A0 = XS_(as[u]); B0 = Whh; X = XS_(xs[u]); O = HS_(os[u]);
  } else if (mode == 2) {
    if (u == 0)      { A0 = HS_(2); B0 = Whh;    X = XS_(2); O = HS_(3); }
    else if (u == 1) { A0 = HS_(2); B0 = PWp(0); X = HS_(4); O = HS_(4); }
    else             { A0 = HS_(1); B0 = PWp(0); X = HS_(8); O = HS_(8); }
  } else {
    if (u == 0)      { A0 = HS_(4); B0 = Whh;    X = XS_(4); O = HS_(5); }
    else if (u == 1) { A0 = HS_(4); B0 = PWp(0); X = HS_(1); O = HS_(6); }
    else if (u == 2) { A0 = HS_(1); B0 = Whh; A1 = HS_(4); B1 = PWp(1);
                       terms = 2;               X = XS_(6); O = HS_(7); }
    else             { A0 = HS_(4); B0 = PWp(2); X = HS_(8); O = HS_(8); }
  }
  const size_t co0 = (size_t)(2 * p_) * 524288;
  const size_t co1 = co0 + 524288;
  const int half = (threadIdx.x >> 6) & 1;            // wave-uniform
  const size_t coh = half ? co1 : co0;
  if (terms == 2)
    pair_tile128T<2>(SH, A0 + co0, A0 + co1, B0, A1 + co0, A1 + co1, B1,
                     n0, X + coh, O + coh, 1);
  else
    pair_tile128T<1>(SH, A0 + co0, A0 + co1, B0, nullptr, nullptr, nullptr,
                     n0, X + coh, O + coh, 1);
}

// -------------------------------------------------------------- scan64 -----
// nw[c] = old[c] + (c>=d ? old[c-d]@Pv^T : 0). Chunk strides 524288.
// nride power-squaring blocks occupy the LOW bids (start early, hide under
// the 256 paired step blocks). Pairs fully below d fast-copy; mixed pairs
// gate the low half in-epilogue.
__global__ __launch_bounds__(256) void scan64(
    const ushort_t* __restrict__ old, ushort_t* __restrict__ nw,
    const ushort_t* __restrict__ Pv, int d,
    const ushort_t* __restrict__ Pra, ushort_t* __restrict__ Pwo, int nride) {
  __shared__ __align__(16) ushort_t SH[16384];       // 32 KB
  if (blockIdx.x < nride) {
    power_tile(SH, Pra, Pra, Pwo, blockIdx.x);
    return;
  }
  const int bid = blockIdx.x - nride;                // nride%8==0 keeps bid%8
  const int p_ = (bid & 7) | (((bid >> 6) & 3) << 3);
  const int n0 = ((bid >> 3) & 7) * 128;
  const int c0 = 2 * p_, c1 = c0 + 1;
  if (c1 < d) {                                      // both halves dead: copy
    copy_tile(old + (size_t)c0 * 524288, nw + (size_t)c0 * 524288, n0);
    copy_tile(old + (size_t)c1 * 524288, nw + (size_t)c1 * 524288, n0);
    return;
  }
  const int ia0 = (c0 >= d) ? (c0 - d) : 0;          // clamped; gated in epi
  const int ia1 = c1 - d;                            // c1 >= d here
  const int half = (threadIdx.x >> 6) & 1;           // wave-uniform
  const int ch = half ? c1 : c0;
  const int gate = (ch >= d);
  pair_tile128T<1>(SH, old + (size_t)ia0 * 524288, old + (size_t)ia1 * 524288,
                   Pv, nullptr, nullptr, nullptr, n0,
                   old + (size_t)ch * 524288, nw + (size_t)ch * 524288, gate);
}

// ----------------------------------------------------------- correction ----
// Round-1-proven body, full 32 pairs. grid (256, 8): j = by+1:
//   Harr[slot j][c] = X_j[c] + S[c]@(W^j)^T, X_1 = XhB slot0, X_j = slot j.
__global__ __launch_bounds__(256) void correct_kernel(
    const ushort_t* __restrict__ S, const ushort_t* __restrict__ XhB,
    ushort_t* __restrict__ Harr, const ushort_t* __restrict__ Whh,
    const ushort_t* __restrict__ Pw) {
  __shared__ __align__(16) ushort_t AsF[2][4096];
  __shared__ __align__(16) ushort_t BsF[2][4096];
  const int p_ = blockIdx.x >> 3;
  const int n0 = (blockIdx.x & 7) * 128;
  const int j = blockIdx.y + 1;
  const ushort_t* Wj = (j == 1) ? Whh : (Pw + (size_t)(j - 2) * 1048576);
  const ushort_t* Xs = (j == 1) ? XhB : (Harr + (size_t)j * 65536);
  ushort_t* XO = Harr + (size_t)j * 65536;
  const int tid = threadIdx.x;
  const int w = tid >> 6, l = tid & 63;
  const int quad = l >> 4, l15 = l & 15;
  const int wm = (w & 1) * 64, wn = (w >> 1) * 64;
  const int r0 = tid >> 2, chunk = tid & 3;
  f32x4 acc[4][4] = {};
  const ushort_t* a0 = S + (size_t)(2 * p_) * 524288 + (size_t)r0 * 1024;
  const ushort_t* a1 = S + (size_t)(2 * p_ + 1) * 524288 + (size_t)r0 * 1024;
  gload16(a0 + chunk * 8, &AsF[0][tid * 8]);
  gload16(a1 + chunk * 8, &AsF[0][2048 + tid * 8]);
  gload16(Wj + (size_t)(n0 + r0) * 1024 + chunk * 8,      &BsF[0][tid * 8]);
  gload16(Wj + (size_t)(n0 + r0 + 64) * 1024 + chunk * 8, &BsF[0][2048 + tid * 8]);
  for (int it = 0; it < 32; ++it) {
    const int p = it & 1;
    __syncthreads();
    if (it < 31) {
      const int kn = (it + 1) * 32;
      gload16(a0 + kn + chunk * 8, &AsF[p ^ 1][tid * 8]);
      gload16(a1 + kn + chunk * 8, &AsF[p ^ 1][2048 + tid * 8]);
      gload16(Wj + (size_t)(n0 + r0) * 1024 + kn + chunk * 8,      &BsF[p ^ 1][tid * 8]);
      gload16(Wj + (size_t)(n0 + r0 + 64) * 1024 + kn + chunk * 8, &BsF[p ^ 1][2048 + tid * 8]);
    }
    bf16x8 af[4], bfr[4];
#pragma unroll
    for (int i = 0; i < 4; ++i) af[i]  = *(const bf16x8*)&AsF[p][(wm + 16 * i + l15) * 32 + 8 * quad];
#pragma unroll
    for (int jj = 0; jj < 4; ++jj) bfr[jj] = *(const bf16x8*)&BsF[p][(wn + 16 * jj + l15) * 32 + 8 * quad];
#pragma unroll
    for (int i = 0; i < 4; ++i)
#pragma unroll
      for (int jj = 0; jj < 4; ++jj)
        acc[i][jj] = __builtin_amdgcn_mfma_f32_16x16x32_bf16(af[i], bfr[jj], acc[i][jj], 0, 0, 0);
  }
#pragma unroll
  for (int i = 0; i < 4; ++i) {
#pragma unroll
    for (int jj = 0; jj < 4; ++jj) {
      const int col = n0 + wn + 16 * jj + l15;
#pragma unroll
      for (int r = 0; r < 4; ++r) {
        const int gr = wm + 16 * i + 4 * quad + r;
        const int c = 2 * p_ + (gr >> 6);
        const size_t idx = (size_t)c * 524288 + (size_t)(gr & 63) * 1024 + col;
        XO[idx] = f2bf(acc[i][jj][r] + bf2f(Xs[idx]));
      }
    }
  }
}

// ---------------------------------------------------------- fused final ----
// oc = xB@U1^T + Hprev@U2^T + Hnew@Wo2^T + bias' ; out = oc * mask (bit mask)
// BK=64: two [128][32] sub-tiles per buffer (identical layout/addressing to
// the proven BK=32 step), both issued per iteration -> 40 iters, 32 MFMA/wave
// per barrier, half the barrier-drain cost. LDS 64KB (2 blocks/CU).
// LDS map (ushorts): A = buf p*8192 + sub ks*4096; B = 16384 + same.
__global__ __launch_bounds__(256) void gemm_fused(
    const ushort_t* __restrict__ xB, const ushort_t* __restrict__ U1,
    const ushort_t* __restrict__ Harr, const ushort_t* __restrict__ U2,
    const ushort_t* __restrict__ Wo2, const float* __restrict__ biasP,
    const uint64_t* __restrict__ maskb, float* __restrict__ out) {
  __shared__ __align__(16) ushort_t SH[32768];       // 64 KB
  const int mt = blockIdx.x & 255, nt = blockIdx.x >> 8;
  const int m0 = mt * 128, n0 = nt * 128;
  const int tid = threadIdx.x;
  const int w = tid >> 6, l = tid & 63;
  const int quad = l >> 4, l15 = l & 15;
  const int wm = (w & 1) * 64, wn = (w >> 1) * 64;
  const int r0 = tid >> 2, chunk = tid & 3;
  f32x4 acc[4][4] = {};
  auto issue = [&](int it, int b) {
    const ushort_t *A, *B; int K, k0;
    if (it < 8)       { A = xB;           B = U1;  K = 512;  k0 = it << 6; }
    else if (it < 24) { A = Harr;         B = U2;  K = 1024; k0 = (it - 8) << 6; }
    else              { A = Harr + 65536; B = Wo2; K = 1024; k0 = (it - 24) << 6; }
    const int ab = b * 8192, bb = 16384 + b * 8192;
#pragma unroll
    for (int ks = 0; ks < 2; ++ks) {
      const int k = k0 + ks * 32;
      const int so = ks * 4096;
      gload16(A + (size_t)(m0 + r0) * K + k + chunk * 8,      &SH[ab + so + tid * 8]);
      gload16(A + (size_t)(m0 + r0 + 64) * K + k + chunk * 8, &SH[ab + so + 2048 + tid * 8]);
      gload16(B + (size_t)(n0 + r0) * K + k + chunk * 8,      &SH[bb + so + tid * 8]);
      gload16(B + (size_t)(n0 + r0 + 64) * K + k + chunk * 8, &SH[bb + so + 2048 + tid * 8]);
    }
  };
  issue(0, 0);
  for (int it = 0; it < 40; ++it) {
    const int p = it & 1;
    __syncthreads();               // drains buf[p] loads; protects buf[p^1]
    if (it < 39) issue(it + 1, p ^ 1);
    const int ap = p * 8192, bp = 16384 + p * 8192;
#pragma unroll
    for (int ks = 0; ks < 2; ++ks) {
      const int so = ks * 4096;
      bf16x8 af[4], bfr[4];
#pragma unroll
      for (int i = 0; i < 4; ++i) af[i]  = *(const bf16x8*)&SH[ap + so + (wm + 16 * i + l15) * 32 + 8 * quad];
#pragma unroll
      for (int j = 0; j < 4; ++j) bfr[j] = *(const bf16x8*)&SH[bp + so + (wn + 16 * j + l15) * 32 + 8 * quad];
#pragma unroll
      for (int i = 0; i < 4; ++i)
#pragma unroll
        for (int j = 0; j < 4; ++j)
          acc[i][j] = __builtin_amdgcn_mfma_f32_16x16x32_bf16(af[i], bfr[j], acc[i][j], 0, 0, 0);
    }
  }
  const float INV_KEEP = 1.0f / 0.7f;     // exact: matches JAX f32 1.0/0.7
#pragma unroll
  for (int i = 0; i < 4; ++i) {
    const int row = m0 + wm + 16 * i + 4 * quad;
#pragma unroll
    for (int j = 0; j < 4; ++j) {
      const int col = n0 + wn + 16 * j + l15;
      const float bv = biasP[col];
#pragma unroll
      for (int r = 0; r < 4; ++r) {
        const size_t idx = (size_t)(row + r) * 512 + col;
        const uint64_t bits = maskb[idx >> 6];
        out[idx] = ((bits >> (idx & 63)) & 1) ? (acc[i][j][r] + bv) * INV_KEEP
                                              : 0.0f;
      }
    }
  }
}

// -------------------------------------------------------------- softmax ----
// Wave-per-row: 512 f32 = 8/lane (2x float4), pure shfl reduce, no LDS.
__global__ __launch_bounds__(256) void softmax_kernel(float* __restrict__ out) {
  const int row = blockIdx.x * 4 + (threadIdx.x >> 6);
  const int lane = threadIdx.x & 63;
  const size_t base = (size_t)row * 512 + (size_t)lane * 8;
  float4 v0 = *(const float4*)&out[base];
  float4 v1 = *(const float4*)&out[base + 4];
  float m = fmaxf(fmaxf(fmaxf(v0.x, v0.y), fmaxf(v0.z, v0.w)),
                  fmaxf(fmaxf(v1.x, v1.y), fmaxf(v1.z, v1.w)));
#pragma unroll
  for (int off = 32; off; off >>= 1) m = fmaxf(m, __shfl_xor(m, off, 64));
  float s = __expf(v0.x - m) + __expf(v0.y - m) + __expf(v0.z - m) +
            __expf(v0.w - m) + __expf(v1.x - m) + __expf(v1.y - m) +
            __expf(v1.z - m) + __expf(v1.w - m);
#pragma unroll
  for (int off = 32; off; off >>= 1) s += __shfl_xor(s, off, 64);
  const float sh = m + logf(s);
  v0.x -= sh; v0.y -= sh; v0.z -= sh; v0.w -= sh;
  v1.x -= sh; v1.y -= sh; v1.z -= sh; v1.w -= sh;
  *(float4*)&out[base] = v0;
  *(float4*)&out[base + 4] = v1;
}

// ---------------------------------------------------------------------------
extern "C" void kernel_launch(void* const* d_in, const int* in_sizes, int n_in,
                              void* d_out, int out_size, void* d_ws, size_t ws_size,
                              hipStream_t stream) {
  const float* x     = (const float*)d_in[0];
  const float* mask  = (const float*)d_in[1];
  const float* W_i2h = (const float*)d_in[2];
  const float* b_i2h = (const float*)d_in[3];
  const float* W_i2o = (const float*)d_in[4];
  const float* b_i2o = (const float*)d_in[5];
  const float* W_o2o = (const float*)d_in[6];
  const float* b_o2o = (const float*)d_in[7];
  float* out = (float*)d_out;

  char* ws = (char*)d_ws;
  const size_t NEED = 207749120;
  if (ws_size < NEED) return;
  ushort_t* xB   = (ushort_t*)(ws + 0);            // [32768,512] bf16
  ushort_t* XhB  = (ushort_t*)(ws + 33554432);     // [64 chunks][8 slots][64,1024]
  // SA/SB: strided overlays of XhB slots 1 / 3 (raw slots 1..7 dead after
  // pass1; slot 0 stays live for correction j=1). Chunk stride 524288.
  ushort_t* SA   = XhB + 65536;
  ushort_t* SB   = XhB + 3 * 65536;
  ushort_t* Harr = (ushort_t*)(ws + 100663296);    // [513][64,1024] bf16
  ushort_t* Pw   = (ushort_t*)(ws + 167903232);    // 12 x [1024,1024] powers
  ushort_t* U1   = (ushort_t*)(ws + 193069056);    // [512,512]
  ushort_t* U2   = (ushort_t*)(ws + 193593344);    // [512,1024]
  float* biasP   = (float*)(ws + 194641920);       // [512] fp32
  uint64_t* maskb = (uint64_t*)(ws + 195000320);   // [262144] u64 (2MB, in gap)
  ushort_t* Wihx = (ushort_t*)(ws + 201457664);
  ushort_t* Whh  = (ushort_t*)(ws + 202506240);
  ushort_t* Wiox = (ushort_t*)(ws + 204603392);
  ushort_t* Wioh = (ushort_t*)(ws + 205127680);
  ushort_t* Wo1  = (ushort_t*)(ws + 206176256);
  ushort_t* Wo2  = (ushort_t*)(ws + 206700544);

  // pack (+ bias' wave-reduce + mask bitpack + Harr slot0 init fold)
  hipLaunchKernelGGL(pack_kernel, dim3(143616), dim3(256), 0, stream,
                     x, mask, W_i2h, W_i2o, W_o2o, b_i2o, b_o2o,
                     xB, Wihx, Whh, Wiox, Wioh, Wo1, Wo2, biasP, maskb,
                     (uint32_t*)Harr);
  // Xh GEMM + usetup ride (48 extra blocks)
  hipLaunchKernelGGL(gemm_bt, dim3(2096), dim3(256), 0, stream,
                     xB, 512, Wihx, 512, b_i2h, XhB, 8,
                     Wo1, Wiox, Wioh, U1, U2);
  // radix-2 pass1: 3 launches, rides first (W2 / W3,W4 / W5..W8)
  hipLaunchKernelGGL(pass_kernel, dim3(1088), dim3(256), 0, stream,
                     XhB, Harr, Whh, Pw, 1);
  hipLaunchKernelGGL(pass_kernel, dim3(896), dim3(256), 0, stream,
                     XhB, Harr, Whh, Pw, 2);
  hipLaunchKernelGGL(pass_kernel, dim3(1280), dim3(256), 0, stream,
                     XhB, Harr, Whh, Pw, 3);
  // Hillis-Steele scan over chunk starts (final S lands in SA). Each of the
  // first 5 rounds rides the next power squaring (W16..W256), rides first.
  hipLaunchKernelGGL(scan64, dim3(320), dim3(256), 0, stream, Harr, SB, PWp(6),  1, PWp(6),  PWp(7),  64);
  hipLaunchKernelGGL(scan64, dim3(320), dim3(256), 0, stream, SB, SA, PWp(7),  2, PWp(7),  PWp(8),  64);
  hipLaunchKernelGGL(scan64, dim3(320), dim3(256), 0, stream, SA, SB, PWp(8),  4, PWp(8),  PWp(9),  64);
  hipLaunchKernelGGL(scan64, dim3(320), dim3(256), 0, stream, SB, SA, PWp(9),  8, PWp(9),  PWp(10), 64);
  hipLaunchKernelGGL(scan64, dim3(320), dim3(256), 0, stream, SA, SB, PWp(10), 16, PWp(10), PWp(11), 64);
  hipLaunchKernelGGL(scan64, dim3(256), dim3(256), 0, stream, SB, SA, PWp(11), 32, (const ushort_t*)nullptr, (ushort_t*)nullptr, 0);
  // correction: Harr[slot j][c] = X_j + S_c @ (W^j)^T, j=1..8
  hipLaunchKernelGGL(correct_kernel, dim3(dim3(256, 8)), dim3(256), 0, stream,
                     SA, XhB, Harr, Whh, Pw);
  // oc = xB@U1^T + Hprev@U2^T + Hnew@Wo2^T + bias', *mask -> d_out
  hipLaunchKernelGGL(gemm_fused, dim3(1024), dim3(256), 0, stream,
                     xB, U1, Harr, U2, Wo2, biasP, maskb, out);
  hipLaunchKernelGGL(softmax_kernel, dim3(8192), dim3(256), 0, stream, out);
}